// Round 1
// baseline (824.057 us; speedup 1.0000x reference)
//
#include <hip/hip_runtime.h>
#include <stdint.h>

#define B_ 4
#define SQ_ 1024
#define SKV_ 2048
#define D_ 1024
#define H_ 16
#define HD_ 64

typedef short v8s __attribute__((ext_vector_type(8)));
typedef float v4f __attribute__((ext_vector_type(4)));

__device__ __forceinline__ unsigned short f2bf(float f) {
  union { float f; unsigned int u; } c; c.f = f;
  unsigned int u = c.u;
  return (unsigned short)((u + 0x7fffu + ((u >> 16) & 1u)) >> 16);
}

// global -> LDS direct copy, 16B per lane. LDS dest must be linear in tid.
__device__ __forceinline__ void gll16(const void* g, void* l) {
  __builtin_amdgcn_global_load_lds((__attribute__((address_space(1))) void*)g,
                                   (__attribute__((address_space(3))) void*)l,
                                   16, 0, 0);
}

// ---------------- fp32 -> bf16 elementwise convert (vectorized) ----------------
__global__ void f2bf_k(const float* __restrict__ in, unsigned short* __restrict__ out, int n4) {
  int i = blockIdx.x * 256 + threadIdx.x;
  if (i < n4) {
    const float4 v = ((const float4*)in)[i];
    ushort4 o;
    o.x = f2bf(v.x); o.y = f2bf(v.y); o.z = f2bf(v.z); o.w = f2bf(v.w);
    ((ushort4*)out)[i] = o;
  }
}

// ---------------- transpose-convert: W[K][N] fp32 -> Wt[N][K] bf16 ----------------
__global__ void tconv_k(const float* __restrict__ W, unsigned short* __restrict__ Wt, int K, int N) {
  __shared__ float t[32][33];
  const int n0 = blockIdx.x * 32, k0 = blockIdx.y * 32;
  const int tx = threadIdx.x, ty = threadIdx.y;  // 32 x 8
#pragma unroll
  for (int r = 0; r < 32; r += 8)
    t[ty + r][tx] = W[(size_t)(k0 + ty + r) * N + (n0 + tx)];
  __syncthreads();
#pragma unroll
  for (int r = 0; r < 32; r += 8)
    Wt[(size_t)(n0 + ty + r) * K + (k0 + tx)] = f2bf(t[tx][ty + r]);
}

// ---------------- bf16 GEMM, m97 structure: C = A(MxK) * Bt(NxK)^T + bias ----------------
// EPI 0: write bf16 Q layout (b,h,sq,hd)        [M=B*SQ, N=D]
// EPI 1: write bf16 K (b,h,skv,hd) and Vt (b,h,hd,skv)  [M=B*SKV, N=2D]
// EPI 2: write fp32 row-major MxN                [out projection]
template <int EPI>
__global__ void gemm_bt(const unsigned short* __restrict__ A,
                        const unsigned short* __restrict__ Bt,
                        const float* __restrict__ bias,
                        unsigned short* __restrict__ O0,
                        unsigned short* __restrict__ O1,
                        float* __restrict__ OF,
                        int M, int N, int K) {
  __shared__ __align__(16) unsigned short As[128 * 32];
  __shared__ __align__(16) unsigned short Bs[128 * 32];
  const int tid = threadIdx.x;
  const int lane = tid & 63;
  const int w = tid >> 6;
  const int wm = w >> 1, wn = w & 1;
  const int l15 = lane & 15, l4 = lane >> 4;
  const int m0 = blockIdx.x * 128;
  const int n0 = blockIdx.y * 128;

  v4f acc[4][4];
#pragma unroll
  for (int i = 0; i < 4; i++)
#pragma unroll
    for (int j = 0; j < 4; j++) acc[i][j] = (v4f){0.f, 0.f, 0.f, 0.f};

  const int sr = tid >> 2;            // staging row 0..63
  const int sc = (tid & 3) * 8;       // staging col (bf16 elems)
  const unsigned short* gA = A + (size_t)(m0 + sr) * K + sc;
  const unsigned short* gB = Bt + (size_t)(n0 + sr) * K + sc;
  unsigned short* lA = &As[tid * 8];
  unsigned short* lB = &Bs[tid * 8];

  for (int k0 = 0; k0 < K; k0 += 32) {
    __syncthreads();
    gll16(gA + k0, lA);
    gll16(gA + (size_t)64 * K + k0, lA + 64 * 32);
    gll16(gB + k0, lB);
    gll16(gB + (size_t)64 * K + k0, lB + 64 * 32);
    __syncthreads();
    v8s af[4], bf[4];
#pragma unroll
    for (int mi = 0; mi < 4; mi++)
      af[mi] = *(const v8s*)&As[(wm * 64 + mi * 16 + l15) * 32 + l4 * 8];
#pragma unroll
    for (int ni = 0; ni < 4; ni++)
      bf[ni] = *(const v8s*)&Bs[(wn * 64 + ni * 16 + l15) * 32 + l4 * 8];
#pragma unroll
    for (int mi = 0; mi < 4; mi++)
#pragma unroll
      for (int ni = 0; ni < 4; ni++)
        acc[mi][ni] = __builtin_amdgcn_mfma_f32_16x16x32_bf16(af[mi], bf[ni], acc[mi][ni], 0, 0, 0);
  }

#pragma unroll
  for (int mi = 0; mi < 4; mi++) {
#pragma unroll
    for (int ni = 0; ni < 4; ni++) {
#pragma unroll
      for (int j = 0; j < 4; j++) {
        const int m = m0 + wm * 64 + mi * 16 + l4 * 4 + j;
        const int n = n0 + wn * 64 + ni * 16 + l15;
        const float v = acc[mi][ni][j] + bias[n];
        if (EPI == 0) {
          const int b = m >> 10, sq = m & 1023, h = n >> 6, hd = n & 63;
          O0[(((size_t)(b * H_ + h)) * SQ_ + sq) * HD_ + hd] = f2bf(v);
        } else if (EPI == 1) {
          const int b = m >> 11, skv = m & 2047;
          if (n < D_) {
            const int h = n >> 6, hd = n & 63;
            O0[(((size_t)(b * H_ + h)) * SKV_ + skv) * HD_ + hd] = f2bf(v);
          } else {
            const int n2 = n - D_;
            const int h = n2 >> 6, hd = n2 & 63;
            O1[(((size_t)(b * H_ + h)) * HD_ + hd) * SKV_ + skv] = f2bf(v);
          }
        } else {
          OF[(size_t)m * N + n] = v;
        }
      }
    }
  }
}

// ---------------- fused cross-attention core ----------------
// grid (SQ/64, H, B), 256 threads = 4 waves x 16 q-rows.
// Pass 1: online (m,l) per row.  Pass 2: recompute S, write fp32 P, PV via MFMA.
__global__ __launch_bounds__(256)
void attn_k(const unsigned short* __restrict__ Qb,
            const unsigned short* __restrict__ Kb,
            const unsigned short* __restrict__ Vtb,
            const float* __restrict__ mask,
            float* __restrict__ AW,
            unsigned short* __restrict__ X) {
  __shared__ __align__(16) unsigned short Ks[64 * 64];
  __shared__ __align__(16) unsigned short Vs[64 * 64];
  __shared__ __align__(16) unsigned short Ps[4][16 * 64];
  __shared__ __align__(16) float mk[SKV_];

  const int tid = threadIdx.x;
  const int lane = tid & 63;
  const int w = tid >> 6;
  const int l15 = lane & 15, l4 = lane >> 4;
  const int qt = blockIdx.x, h = blockIdx.y, b = blockIdx.z;
  const int bh = b * H_ + h;

  for (int i = tid; i < SKV_ / 4; i += 256)
    ((float4*)mk)[i] = ((const float4*)(mask + (size_t)b * SKV_))[i];

  // Q fragments held in registers (wave covers rows w*16..w*16+15)
  const int qrow = qt * 64 + w * 16 + l15;
  const size_t qbase = ((size_t)bh * SQ_ + qrow) * HD_;
  const v8s qf0 = *(const v8s*)&Qb[qbase + l4 * 8];
  const v8s qf1 = *(const v8s*)&Qb[qbase + 32 + l4 * 8];

  const int srow = tid >> 3;  // staging row 0..31
  const int sg = tid & 7;     // 16B granule within 128B row
  const size_t kgbase = (size_t)bh * SKV_ * HD_;
  const size_t vgbase = (size_t)bh * HD_ * SKV_;

  float ml[4], ll[4];
#pragma unroll
  for (int j = 0; j < 4; j++) { ml[j] = -1e30f; ll[j] = 0.f; }

  // ---- pass 1: row max / sum ----
  for (int t = 0; t < SKV_ / 64; ++t) {
    const int kv0 = t * 64;
    __syncthreads();
    gll16(&Kb[kgbase + (size_t)(kv0 + srow) * HD_ + (sg ^ (srow & 7)) * 8], &Ks[tid * 8]);
    gll16(&Kb[kgbase + (size_t)(kv0 + srow + 32) * HD_ + (sg ^ ((srow + 32) & 7)) * 8], &Ks[2048 + tid * 8]);
    __syncthreads();

    v4f s[4];
#pragma unroll
    for (int kf = 0; kf < 4; kf++) {
      const int kr = kf * 16 + l15;
      const v8s b0 = *(const v8s*)&Ks[kr * 64 + ((l4 ^ (kr & 7)) * 8)];
      const v8s b1 = *(const v8s*)&Ks[kr * 64 + (((l4 + 4) ^ (kr & 7)) * 8)];
      v4f a = (v4f){0.f, 0.f, 0.f, 0.f};
      a = __builtin_amdgcn_mfma_f32_16x16x32_bf16(qf0, b0, a, 0, 0, 0);
      a = __builtin_amdgcn_mfma_f32_16x16x32_bf16(qf1, b1, a, 0, 0, 0);
      s[kf] = a;
    }
    float sv[4][4];
#pragma unroll
    for (int kf = 0; kf < 4; kf++) {
      const float mval = mk[kv0 + kf * 16 + l15];
#pragma unroll
      for (int j = 0; j < 4; j++) sv[kf][j] = s[kf][j] * 0.125f + mval;
    }
#pragma unroll
    for (int j = 0; j < 4; j++) {
      const float mx = fmaxf(fmaxf(sv[0][j], sv[1][j]), fmaxf(sv[2][j], sv[3][j]));
      const float mn = fmaxf(ml[j], mx);
      ll[j] = ll[j] * __expf(ml[j] - mn)
            + __expf(sv[0][j] - mn) + __expf(sv[1][j] - mn)
            + __expf(sv[2][j] - mn) + __expf(sv[3][j] - mn);
      ml[j] = mn;
    }
  }
  // reduce (m,l) across the 16-lane column group
#pragma unroll
  for (int j = 0; j < 4; j++) {
    float m = ml[j], l = ll[j];
#pragma unroll
    for (int off = 1; off < 16; off <<= 1) {
      const float mo = __shfl_xor(m, off);
      const float lo = __shfl_xor(l, off);
      const float mn = fmaxf(m, mo);
      l = l * __expf(m - mn) + lo * __expf(mo - mn);
      m = mn;
    }
    ml[j] = m;
    ll[j] = 1.f / l;
  }

  v4f oa[4];
#pragma unroll
  for (int nf = 0; nf < 4; nf++) oa[nf] = (v4f){0.f, 0.f, 0.f, 0.f};

  float* awbase = AW + ((size_t)bh * SQ_ + qt * 64 + w * 16) * SKV_;

  // ---- pass 2: P write + PV ----
  for (int t = 0; t < SKV_ / 64; ++t) {
    const int kv0 = t * 64;
    __syncthreads();
    gll16(&Kb[kgbase + (size_t)(kv0 + srow) * HD_ + (sg ^ (srow & 7)) * 8], &Ks[tid * 8]);
    gll16(&Kb[kgbase + (size_t)(kv0 + srow + 32) * HD_ + (sg ^ ((srow + 32) & 7)) * 8], &Ks[2048 + tid * 8]);
    gll16(&Vtb[vgbase + (size_t)srow * SKV_ + kv0 + (sg ^ (srow & 7)) * 8], &Vs[tid * 8]);
    gll16(&Vtb[vgbase + (size_t)(srow + 32) * SKV_ + kv0 + (sg ^ ((srow + 32) & 7)) * 8], &Vs[2048 + tid * 8]);
    __syncthreads();

    v4f s[4];
#pragma unroll
    for (int kf = 0; kf < 4; kf++) {
      const int kr = kf * 16 + l15;
      const v8s b0 = *(const v8s*)&Ks[kr * 64 + ((l4 ^ (kr & 7)) * 8)];
      const v8s b1 = *(const v8s*)&Ks[kr * 64 + (((l4 + 4) ^ (kr & 7)) * 8)];
      v4f a = (v4f){0.f, 0.f, 0.f, 0.f};
      a = __builtin_amdgcn_mfma_f32_16x16x32_bf16(qf0, b0, a, 0, 0, 0);
      a = __builtin_amdgcn_mfma_f32_16x16x32_bf16(qf1, b1, a, 0, 0, 0);
      s[kf] = a;
    }
#pragma unroll
    for (int kf = 0; kf < 4; kf++) {
      const int kvc = kf * 16 + l15;
      const float mval = mk[kv0 + kvc];
#pragma unroll
      for (int j = 0; j < 4; j++) {
        const float svv = s[kf][j] * 0.125f + mval;
        const float p = __expf(svv - ml[j]) * ll[j];
        const int q = l4 * 4 + j;
        awbase[(size_t)q * SKV_ + kv0 + kvc] = p;
        Ps[w][q * 64 + (((kvc >> 3) ^ (q & 7)) * 8) + (kvc & 7)] = f2bf(p);
      }
    }
    asm volatile("s_waitcnt lgkmcnt(0)" ::: "memory");
    __builtin_amdgcn_sched_barrier(0);
#pragma unroll
    for (int kk = 0; kk < 2; kk++) {
      const v8s pf = *(const v8s*)&Ps[w][l15 * 64 + (((l4 + kk * 4) ^ (l15 & 7)) * 8)];
#pragma unroll
      for (int nf = 0; nf < 4; nf++) {
        const int hd = nf * 16 + l15;
        const v8s vf = *(const v8s*)&Vs[hd * 64 + (((l4 + kk * 4) ^ (hd & 7)) * 8)];
        oa[nf] = __builtin_amdgcn_mfma_f32_16x16x32_bf16(pf, vf, oa[nf], 0, 0, 0);
      }
    }
  }

#pragma unroll
  for (int nf = 0; nf < 4; nf++) {
#pragma unroll
    for (int j = 0; j < 4; j++) {
      const int q = qt * 64 + w * 16 + l4 * 4 + j;
      X[((size_t)b * SQ_ + q) * D_ + h * HD_ + nf * 16 + l15] = f2bf(oa[nf][j]);
    }
  }
}

extern "C" void kernel_launch(void* const* d_in, const int* in_sizes, int n_in,
                              void* d_out, int out_size, void* d_ws, size_t ws_size,
                              hipStream_t stream) {
  (void)in_sizes; (void)n_in; (void)out_size; (void)ws_size;
  const float* hidden = (const float*)d_in[0];
  const float* enc    = (const float*)d_in[1];
  const float* mask   = (const float*)d_in[2];
  const float* qw     = (const float*)d_in[3];
  const float* qb     = (const float*)d_in[4];
  const float* cw     = (const float*)d_in[5];
  const float* cb     = (const float*)d_in[6];
  const float* pw     = (const float*)d_in[7];
  const float* pb     = (const float*)d_in[8];

  float* out = (float*)d_out;
  float* aw  = out + (size_t)B_ * SQ_ * D_;

  char* ws = (char*)d_ws;
  unsigned short* hbf = (unsigned short*)(ws + (size_t)(0u)  * (1u << 20));  //  8 MB
  unsigned short* ebf = (unsigned short*)(ws + (size_t)(8u)  * (1u << 20));  // 16 MB
  unsigned short* qwt = (unsigned short*)(ws + (size_t)(24u) * (1u << 20));  //  2 MB
  unsigned short* cat = (unsigned short*)(ws + (size_t)(26u) * (1u << 20));  //  4 MB
  unsigned short* cpt = (unsigned short*)(ws + (size_t)(30u) * (1u << 20));  //  2 MB
  unsigned short* Qb  = (unsigned short*)(ws + (size_t)(32u) * (1u << 20));  //  8 MB
  unsigned short* Kb  = (unsigned short*)(ws + (size_t)(40u) * (1u << 20));  // 16 MB
  unsigned short* Vtb = (unsigned short*)(ws + (size_t)(56u) * (1u << 20));  // 16 MB
  unsigned short* Xb  = (unsigned short*)(ws + (size_t)(72u) * (1u << 20));  //  8 MB (total 80 MB)

  hipLaunchKernelGGL(f2bf_k, dim3((B_ * SQ_ * D_ / 4 + 255) / 256), dim3(256), 0, stream,
                     hidden, hbf, B_ * SQ_ * D_ / 4);
  hipLaunchKernelGGL(f2bf_k, dim3((B_ * SKV_ * D_ / 4 + 255) / 256), dim3(256), 0, stream,
                     enc, ebf, B_ * SKV_ * D_ / 4);
  hipLaunchKernelGGL(tconv_k, dim3(D_ / 32, D_ / 32), dim3(32, 8), 0, stream, qw, qwt, D_, D_);
  hipLaunchKernelGGL(tconv_k, dim3(2 * D_ / 32, D_ / 32), dim3(32, 8), 0, stream, cw, cat, D_, 2 * D_);
  hipLaunchKernelGGL(tconv_k, dim3(D_ / 32, D_ / 32), dim3(32, 8), 0, stream, pw, cpt, D_, D_);

  hipLaunchKernelGGL(gemm_bt<0>, dim3(B_ * SQ_ / 128, D_ / 128), dim3(256), 0, stream,
                     hbf, qwt, qb, Qb, (unsigned short*)nullptr, (float*)nullptr, B_ * SQ_, D_, D_);
  hipLaunchKernelGGL(gemm_bt<1>, dim3(B_ * SKV_ / 128, 2 * D_ / 128), dim3(256), 0, stream,
                     ebf, cat, cb, Kb, Vtb, (float*)nullptr, B_ * SKV_, 2 * D_, D_);
  hipLaunchKernelGGL(attn_k, dim3(SQ_ / 64, H_, B_), dim3(256), 0, stream,
                     Qb, Kb, Vtb, mask, aw, Xb);
  hipLaunchKernelGGL(gemm_bt<2>, dim3(B_ * SQ_ / 128, D_ / 128), dim3(256), 0, stream,
                     Xb, cpt, pb, (unsigned short*)nullptr, (unsigned short*)nullptr, out, B_ * SQ_, D_, D_);
}